// Round 5
// baseline (565.065 us; speedup 1.0000x reference)
//
#include <hip/hip_runtime.h>

#define LL 50
#define TT 1024
#define BB 256
#define START_I 47
#define END_I 48
#define NW 8                     // waves (blocks) in fwd kernel, 32 chains each
#define NPREB 2048               // prepass blocks (256 thr = 4 waves each)
#define FOFF (TT * NW * 2048)    // floats in fbuf = 16,777,216 (64 MB)

typedef __attribute__((ext_vector_type(8))) short bh8;    // 8 bf16 (MFMA A/B frag)
typedef __attribute__((ext_vector_type(16))) float fx16;  // MFMA C/D frag
typedef __attribute__((ext_vector_type(4))) float fx4;
typedef __attribute__((ext_vector_type(4))) unsigned int ux4;

__device__ __forceinline__ unsigned int cvtpk_bf16(float lo, float hi) {
  unsigned int r;
  asm("v_cvt_pk_bf16_f32 %0, %1, %2" : "=v"(r) : "v"(lo), "v"(hi));
  return r;
}
__device__ __forceinline__ float bpermf(int addr, float x) {
  return __int_as_float(__builtin_amdgcn_ds_bpermute(addr, __float_as_int(x)));
}
__device__ __forceinline__ unsigned int bpermu(int addr, unsigned int x) {
  return (unsigned int)__builtin_amdgcn_ds_bpermute(addr, (int)x);
}
__device__ __forceinline__ float rdlane(float v, int i) {
  return __int_as_float(__builtin_amdgcn_readlane(__float_as_int(v), i));
}

// ============================================================================
// Pre-pass: fbuf[t][w][q][lane][j] = exp(lstm[chain][t][state]), arranged in
// exact MFMA D-fragment order (chain = 32w + (lane&31), h = lane>>5,
// state = 32*(q>>2) + 8*(q&3) + 4h + j; 0 for state >= 50).
// Blocks >= NPREB compute the labeled-path partial sums (4 per b).
// ============================================================================
__global__ __launch_bounds__(256) void crf_prep(
    const float* __restrict__ lstm, const float* __restrict__ trans,
    const int* __restrict__ lens, const int* __restrict__ tags,
    float* __restrict__ fbuf, float* __restrict__ wsf) {
  if (blockIdx.x < NPREB) {
    const int wg = blockIdx.x * 4 + (threadIdx.x >> 6);  // 0..8191
    const int t = wg >> 3, w = wg & 7;
    const int lane = threadIdx.x & 63;
    const int h = lane >> 5, c31 = lane & 31;
    const int chain = w * 32 + c31;
    const float* row = lstm + ((size_t)chain * TT + t) * LL;
    fx4* dst = (fx4*)(fbuf + ((size_t)t * 8 + w) * 2048);
#pragma unroll
    for (int q = 0; q < 8; ++q) {
      fx4 v;
#pragma unroll
      for (int j = 0; j < 4; ++j) {
        int s = 32 * (q >> 2) + 8 * (q & 3) + 4 * h + j;
        v[j] = (s < LL) ? __expf(row[s]) : 0.f;
      }
      dst[q * 64 + lane] = v;
    }
  } else {
    const int b = blockIdx.x - NPREB;
    const int tid = threadIdx.x;
    const int* tg = tags + (size_t)b * TT;
    const int len = lens[b];
    float lab = 0.f;
    for (int t = 1 + tid; t < len; t += 256) {
      int tp = tg[t - 1], tc = tg[t];
      lab += trans[tp * LL + tc] + lstm[((size_t)b * TT + t) * LL + tc];
    }
#pragma unroll
    for (int off = 32; off > 0; off >>= 1) lab += __shfl_xor(lab, off, 64);
    if ((tid & 63) == 0) {
      int widx = tid >> 6;
      if (widx == 0) {
        int tg0 = tg[0], tgl = tg[len - 1];
        lab += trans[START_I * LL + tg0] + lstm[(size_t)b * TT * LL + tg0] +
               trans[tgl * LL + END_I];
      }
      wsf[BB + 4 * b + widx] = lab;
    }
  }
}

// ============================================================================
// Serial forward: 8 waves, 32 chains each. Recurrence in scaled-linear domain:
//   q' = (E^T q) o f,  E = exp(trans) in bf16, one mfma_f32_32x32x16_bf16
//   K-chain (2 M-tiles x 4 K-chunks) per step for all 32 chains.
// D layout (m74-verified): chain = lane&31, state = (r&3)+8*(r>>2)+4*(lane>>5)
//   (+32 per tile). A/B frags: M/N idx = lane&31, k = (lane>>5)*8 + d.
// D -> next B needs only a lane <-> lane^32 exchange (ds_bpermute + cndmask).
// Per-chain lazy rescale by 2^-64 every 2 steps keeps q in f32 range.
// ============================================================================
__global__ __launch_bounds__(64) __attribute__((amdgpu_waves_per_eu(1, 1)))
void crf_fwd_mfma(const float* __restrict__ trans, const int* __restrict__ lens,
                  const float* __restrict__ fbuf, float* __restrict__ wsf) {
  const int w = blockIdx.x;
  const int lane = threadIdx.x;
  const int h = lane >> 5;
  const int c31 = lane & 31;
  const int chain = w * 32 + c31;
  const int len = lens[chain];
  const bool hi = (h == 1);
  const int bpa = (lane ^ 32) << 2;

  // ---- A fragments: A[T][c], A[m][k] = exp(trans[state_in][state_out]) ----
  bh8 afr[2][4];
#pragma unroll
  for (int T = 0; T < 2; ++T)
#pragma unroll
    for (int c = 0; c < 4; ++c) {
      float ev[8];
#pragma unroll
      for (int d = 0; d < 8; ++d) {
        int si = 16 * c + 8 * h + d, so = 32 * T + c31;
        ev[d] = (si < LL && so < LL) ? __expf(trans[si * LL + so]) : 0.f;
      }
      ux4 dw = {cvtpk_bf16(ev[0], ev[1]), cvtpk_bf16(ev[2], ev[3]),
                cvtpk_bf16(ev[4], ev[5]), cvtpk_bf16(ev[6], ev[7])};
      afr[T][c] = __builtin_bit_cast(bh8, dw);
    }

  // ---- exp(trans[s][END]) in D layout ----
  float ee0[16], ee1[16];
#pragma unroll
  for (int r = 0; r < 16; ++r) {
    int sa = (r & 3) + 8 * (r >> 2) + 4 * h;
    ee0[r] = __expf(trans[sa * LL + END_I]);  // sa <= 31 < 50
    int s1 = 32 + sa;
    ee1[r] = (s1 < LL) ? __expf(trans[s1 * LL + END_I]) : 0.f;
  }

  // ---- f prefetch (2 steps deep; fbuf is L3-resident) ----
  const fx4* __restrict__ fp = (const fx4*)fbuf;
  fx4 fqA[8], fqB[8];
  auto LOADF = [&](int t, fx4(&fq)[8]) {
    size_t bqd = ((size_t)t * NW + w) * 512 + lane;
#pragma unroll
    for (int i = 0; i < 8; ++i) fq[i] = fp[bqd + i * 64];
  };
  LOADF(0, fqA);
  LOADF(1, fqB);

  int cnt = 0, cc = 0;
  float Zc = 1.0f;
  bh8 bq[4];
  fx16 z16 = {};

  // ---- step tail: rescale / capture / pack+exchange -> bq ----
  auto TAIL = [&](int t, float(&d0)[16], float(&d1)[16]) {
    if (t & 1) {  // per-chain lazy rescale, checked every 2nd step
      float m = d0[0];
#pragma unroll
      for (int r = 1; r < 16; ++r) m = fmaxf(m, d0[r]);
#pragma unroll
      for (int r = 0; r < 16; ++r) m = fmaxf(m, d1[r]);
      m = fmaxf(m, bpermf(bpa, m));  // chain max (lanes l, l^32)
      bool trig = (m >= 0x1p64f);
      if (__any(trig)) {
        float s = trig ? 0x1p-64f : 1.0f;
        cnt += trig ? 1 : 0;
#pragma unroll
        for (int r = 0; r < 16; ++r) {
          d0[r] *= s;
          d1[r] *= s;
        }
      }
    }
    if (__any(len == t + 1)) {  // capture sum_j q_j * exp(trans[j][END])
      float z = 0.f;
#pragma unroll
      for (int r = 0; r < 16; ++r) z = fmaf(d0[r], ee0[r], z);
#pragma unroll
      for (int r = 0; r < 16; ++r) z = fmaf(d1[r], ee1[r], z);
      z += bpermf(bpa, z);
      if (len == t + 1) {
        Zc = z;
        cc = cnt;
      }
    }
    // pack D -> bf16 pair dwords, cross-half exchange, assemble B frags
    unsigned int P0[8], P1[8], Q0[8], Q1[8];
#pragma unroll
    for (int p = 0; p < 8; ++p) {
      P0[p] = cvtpk_bf16(d0[2 * p], d0[2 * p + 1]);
      P1[p] = cvtpk_bf16(d1[2 * p], d1[2 * p + 1]);
    }
#pragma unroll
    for (int p = 0; p < 8; ++p) {
      Q0[p] = bpermu(bpa, P0[p]);
      Q1[p] = bpermu(bpa, P1[p]);
    }
#define BUILDB(ci, Pv, Qv)                            \
  {                                                   \
    enum { A_ = 4 * ((ci) & 1) };                     \
    unsigned int w0 = hi ? Qv[A_ + 2] : Pv[A_ + 0];   \
    unsigned int w1 = hi ? Qv[A_ + 3] : Pv[A_ + 1];   \
    unsigned int w2 = hi ? Pv[A_ + 2] : Qv[A_ + 0];   \
    unsigned int w3 = hi ? Pv[A_ + 3] : Qv[A_ + 1];   \
    ux4 dw_ = {w0, w1, w2, w3};                       \
    bq[ci] = __builtin_bit_cast(bh8, dw_);            \
  }
    BUILDB(0, P0, Q0)
    BUILDB(1, P0, Q0)
    BUILDB(2, P1, Q1)
    BUILDB(3, P1, Q1)
#undef BUILDB
  };

  // ---- t = 0: q0 = exp(trans[START][s]) * f0 ----
  {
    float d0[16], d1[16];
#pragma unroll
    for (int r = 0; r < 16; ++r) {
      int sa = (r & 3) + 8 * (r >> 2) + 4 * h;
      float e0 = __expf(trans[START_I * LL + sa]);
      int s1 = 32 + sa;
      float e1 = (s1 < LL) ? __expf(trans[START_I * LL + s1]) : 0.f;
      d0[r] = e0 * fqA[r >> 2][r & 3];
      d1[r] = e1 * fqA[4 + (r >> 2)][r & 3];
    }
    TAIL(0, d0, d1);
    LOADF(2, fqA);
  }

  auto STEP = [&](int t, fx4(&fq)[8]) {
    fx16 ac0, ac1;
    ac0 = __builtin_amdgcn_mfma_f32_32x32x16_bf16(afr[0][0], bq[0], z16, 0, 0, 0);
    ac1 = __builtin_amdgcn_mfma_f32_32x32x16_bf16(afr[1][0], bq[0], z16, 0, 0, 0);
    ac0 = __builtin_amdgcn_mfma_f32_32x32x16_bf16(afr[0][1], bq[1], ac0, 0, 0, 0);
    ac1 = __builtin_amdgcn_mfma_f32_32x32x16_bf16(afr[1][1], bq[1], ac1, 0, 0, 0);
    ac0 = __builtin_amdgcn_mfma_f32_32x32x16_bf16(afr[0][2], bq[2], ac0, 0, 0, 0);
    ac1 = __builtin_amdgcn_mfma_f32_32x32x16_bf16(afr[1][2], bq[2], ac1, 0, 0, 0);
    ac0 = __builtin_amdgcn_mfma_f32_32x32x16_bf16(afr[0][3], bq[3], ac0, 0, 0, 0);
    ac1 = __builtin_amdgcn_mfma_f32_32x32x16_bf16(afr[1][3], bq[3], ac1, 0, 0, 0);
    float d0[16], d1[16];
#pragma unroll
    for (int r = 0; r < 16; ++r) {
      d0[r] = ac0[r] * fq[r >> 2][r & 3];
      d1[r] = ac1[r] * fq[4 + (r >> 2)][r & 3];
    }
    if (t + 2 < TT) LOADF(t + 2, fq);
    TAIL(t, d0, d1);
  };

  for (int t = 1; t < TT - 1; t += 2) {
    STEP(t, fqB);
    STEP(t + 1, fqA);
  }
  STEP(TT - 1, fqB);

  if (lane < 32)
    wsf[chain] = (float)cc * 44.361419555836498f + __logf(Zc);
}

// ============================================================================
// Legacy fallback (proven round-3 kernel), used when ws_size < 64 MB staging.
// ============================================================================
__global__ __launch_bounds__(64) __attribute__((amdgpu_waves_per_eu(1, 1)))
void crf_fwd_legacy(
    const float* __restrict__ lstm, const float* __restrict__ trans,
    const int* __restrict__ lens, const int* __restrict__ tags,
    float* __restrict__ ws) {
  const int b = blockIdx.x;
  const int lane = threadIdx.x;
  const bool act = lane < LL;
  const int cl = act ? lane : (LL - 1);
  const int len = lens[b];

  float e[LL];
#pragma unroll
  for (int i = 0; i < LL; ++i) {
    float ev = __expf(trans[i * LL + cl]);
    e[i] = act ? ev : 0.0f;
  }
  const float* __restrict__ base = lstm + (size_t)b * TT * LL + cl;
  float q = act ? __expf(trans[START_I * LL + lane] + base[0]) : 0.0f;
  int cnt = 0;
  float s_pend = 1.0f;

  auto STEP = [&](float em) {
    float f = __expf(em) * s_pend;
    float acc0 = 0.f, acc1 = 0.f, acc2 = 0.f, acc3 = 0.f;
#pragma unroll
    for (int i = 0; i < 48; i += 4) {
      acc0 = fmaf(rdlane(q, i + 0), e[i + 0], acc0);
      acc1 = fmaf(rdlane(q, i + 1), e[i + 1], acc1);
      acc2 = fmaf(rdlane(q, i + 2), e[i + 2], acc2);
      acc3 = fmaf(rdlane(q, i + 3), e[i + 3], acc3);
    }
    acc0 = fmaf(rdlane(q, 48), e[48], acc0);
    acc1 = fmaf(rdlane(q, 49), e[49], acc1);
    float qn = ((acc0 + acc1) + (acc2 + acc3)) * f;
    unsigned long long up = __ballot(qn >= 0x1p64f);
    unsigned long long dn = __ballot(qn >= 0x1p-64f);
    s_pend = up ? 0x1p-64f : (dn ? 1.0f : 0x1p64f);
    cnt += up ? 1 : (dn ? 0 : -1);
    q = qn;
  };

  float ebuf[8];
  const float* p = base + LL;
#pragma unroll
  for (int k = 0; k < 8; ++k) ebuf[k] = p[k * LL];
  const int nb = (len - 1) >> 3;
  const int rem = (len - 1) & 7;
  for (int blk = 0; blk < nb; ++blk) {
    const float* pf = p + 8 * LL;
    if (blk < 126) {
#pragma unroll
      for (int u = 0; u < 8; ++u) {
        STEP(ebuf[u]);
        ebuf[u] = pf[u * LL];
      }
    } else {
#pragma unroll
      for (int u = 0; u < 8; ++u) {
        STEP(ebuf[u]);
        int tn = 9 + 8 * blk + u;
        if (tn < TT) ebuf[u] = pf[u * LL];
      }
    }
    p = pf;
  }
  for (int u = 0; u < rem; ++u) STEP(ebuf[u]);
  q *= s_pend;

  float wv = 0.0f;
  if (act) wv = q * __expf(trans[lane * LL + END_I]);
#pragma unroll
  for (int off = 32; off > 0; off >>= 1) wv += __shfl_xor(wv, off, 64);
  float unl = (float)cnt * 44.361419555836498f + __logf(wv);

  const int* tg = tags + (size_t)b * TT;
  float lab = 0.0f;
  for (int t0 = 0; t0 < len; t0 += 64) {
    int t = t0 + lane;
    if (t >= 1 && t < len) {
      int tp = tg[t - 1];
      int tc = tg[t];
      lab += trans[tp * LL + tc] + lstm[((size_t)b * TT + t) * LL + tc];
    }
  }
#pragma unroll
  for (int off = 32; off > 0; off >>= 1) lab += __shfl_xor(lab, off, 64);

  if (lane == 0) {
    int tg0 = tg[0];
    float begin = trans[START_I * LL + tg0] + lstm[(size_t)b * TT * LL + tg0];
    int tgl = tg[len - 1];
    float endv = trans[tgl * LL + END_I];
    ws[b] = unl;
    ws[BB + 4 * b] = lab + begin + endv;
    ws[BB + 4 * b + 1] = 0.f;
    ws[BB + 4 * b + 2] = 0.f;
    ws[BB + 4 * b + 3] = 0.f;
  }
}

// Deterministic final reduce: base[0..255] -> out[0]; base[256..1279] -> out[1]
__global__ __launch_bounds__(256) void crf_reduce(const float* __restrict__ base,
                                                  float* __restrict__ out) {
  __shared__ float sm[8];
  int tid = threadIdx.x;
  float u = base[tid];
  fx4 lv = ((const fx4*)(base + BB))[tid];
  float l = (lv[0] + lv[1]) + (lv[2] + lv[3]);
#pragma unroll
  for (int off = 32; off > 0; off >>= 1) {
    u += __shfl_xor(u, off, 64);
    l += __shfl_xor(l, off, 64);
  }
  int wid = tid >> 6;
  if ((tid & 63) == 0) {
    sm[wid] = u;
    sm[4 + wid] = l;
  }
  __syncthreads();
  if (tid == 0) {
    out[0] = (sm[0] + sm[1]) + (sm[2] + sm[3]);
    out[1] = (sm[4] + sm[5]) + (sm[6] + sm[7]);
  }
}

extern "C" void kernel_launch(void* const* d_in, const int* in_sizes, int n_in,
                              void* d_out, int out_size, void* d_ws, size_t ws_size,
                              hipStream_t stream) {
  const float* lstm = (const float*)d_in[0];
  const float* trans = (const float*)d_in[1];
  const int* lens = (const int*)d_in[2];
  const int* tags = (const int*)d_in[3];
  float* out = (float*)d_out;

  size_t need = (size_t)FOFF * 4 + (size_t)(BB * 5) * 4;
  if (ws_size >= need) {
    float* fbuf = (float*)d_ws;
    float* wsf = fbuf + FOFF;
    crf_prep<<<dim3(NPREB + BB), dim3(256), 0, stream>>>(lstm, trans, lens, tags,
                                                         fbuf, wsf);
    crf_fwd_mfma<<<dim3(NW), dim3(64), 0, stream>>>(trans, lens, fbuf, wsf);
    crf_reduce<<<dim3(1), dim3(256), 0, stream>>>(wsf, out);
  } else {
    float* wsf = (float*)d_ws;
    crf_fwd_legacy<<<dim3(BB), dim3(64), 0, stream>>>(lstm, trans, lens, tags, wsf);
    crf_reduce<<<dim3(1), dim3(256), 0, stream>>>(wsf, out);
  }
}

// Round 6
// 444.851 us; speedup vs baseline: 1.2702x; 1.2702x over previous
//
#include <hip/hip_runtime.h>

#define LL 50
#define TT 1024
#define BB 256
#define START_I 47
#define END_I 48
#define NW 8                     // waves (blocks) in fwd kernel, 32 chains each
#define NPREB 2048               // prepass blocks (256 thr = 4 waves each)
#define FOFF (TT * NW * 2048)    // floats in fbuf = 16,777,216 (64 MB)

typedef __attribute__((ext_vector_type(8))) short bh8;    // 8 bf16 (MFMA A/B frag)
typedef __attribute__((ext_vector_type(16))) float fx16;  // MFMA C/D frag
typedef __attribute__((ext_vector_type(4))) float fx4;
typedef __attribute__((ext_vector_type(4))) unsigned int ux4;

__device__ __forceinline__ unsigned int cvtpk_bf16(float lo, float hi) {
  unsigned int r;
  asm("v_cvt_pk_bf16_f32 %0, %1, %2" : "=v"(r) : "v"(lo), "v"(hi));
  return r;
}
// v_permlane32_swap_b32: vdst.hi <-> vsrc.lo  (VALU cross-half exchange)
__device__ __forceinline__ void pls(unsigned int& a, unsigned int& b) {
  asm("v_permlane32_swap_b32 %0, %1" : "+v"(a), "+v"(b));
}
// value of the paired lane (l ^ 32); full-exec contexts only
__device__ __forceinline__ float xpart(float x, bool hi) {
  unsigned int a = __float_as_uint(x), b = a;
  pls(a, b);
  return __uint_as_float(hi ? a : b);
}
__device__ __forceinline__ float rdlane(float v, int i) {
  return __int_as_float(__builtin_amdgcn_readlane(__float_as_int(v), i));
}

// ============================================================================
// Pre-pass: fbuf[t][w][q][lane][j] = exp(lstm[chain][t][state]), arranged in
// exact MFMA D-fragment order (chain = 32w + (lane&31), h = lane>>5,
// state = 32*(q>>2) + 8*(q&3) + 4h + j; 0 for state >= 50).
// Blocks >= NPREB compute the labeled-path partial sums (4 per b).
// ============================================================================
__global__ __launch_bounds__(256) void crf_prep(
    const float* __restrict__ lstm, const float* __restrict__ trans,
    const int* __restrict__ lens, const int* __restrict__ tags,
    float* __restrict__ fbuf, float* __restrict__ wsf) {
  if (blockIdx.x < NPREB) {
    const int wg = blockIdx.x * 4 + (threadIdx.x >> 6);  // 0..8191
    const int t = wg >> 3, w = wg & 7;
    const int lane = threadIdx.x & 63;
    const int h = lane >> 5, c31 = lane & 31;
    const int chain = w * 32 + c31;
    const float* row = lstm + ((size_t)chain * TT + t) * LL;
    fx4* dst = (fx4*)(fbuf + ((size_t)t * 8 + w) * 2048);
#pragma unroll
    for (int q = 0; q < 8; ++q) {
      fx4 v;
#pragma unroll
      for (int j = 0; j < 4; ++j) {
        int s = 32 * (q >> 2) + 8 * (q & 3) + 4 * h + j;
        v[j] = (s < LL) ? __expf(row[s]) : 0.f;
      }
      dst[q * 64 + lane] = v;
    }
  } else {
    const int b = blockIdx.x - NPREB;
    const int tid = threadIdx.x;
    const int* tg = tags + (size_t)b * TT;
    const int len = lens[b];
    float lab = 0.f;
    for (int t = 1 + tid; t < len; t += 256) {
      int tp = tg[t - 1], tc = tg[t];
      lab += trans[tp * LL + tc] + lstm[((size_t)b * TT + t) * LL + tc];
    }
#pragma unroll
    for (int off = 32; off > 0; off >>= 1) lab += __shfl_xor(lab, off, 64);
    if ((tid & 63) == 0) {
      int widx = tid >> 6;
      if (widx == 0) {
        int tg0 = tg[0], tgl = tg[len - 1];
        lab += trans[START_I * LL + tg0] + lstm[(size_t)b * TT * LL + tg0] +
               trans[tgl * LL + END_I];
      }
      wsf[BB + 4 * b + widx] = lab;
    }
  }
}

// ============================================================================
// Serial forward: 8 waves, 32 chains each. q' = (E^T q) o f, one
// mfma_f32_32x32x16_bf16 K-chain (2 M-tiles x 4 K-chunks) per step.
// D layout (m74): chain = lane&31, state = (r&3)+8*(r>>2)+4*(lane>>5).
// D -> next B via 8x v_permlane32_swap (VALU) instead of ds_bpermute.
// Rescale: detect at odd t (max-tree + swap + ballot), APPLY to next step's
// fq while that step's MFMAs are in flight (off the serial critical path).
// ============================================================================
__global__ __launch_bounds__(64) __attribute__((amdgpu_waves_per_eu(1, 1)))
void crf_fwd_mfma(const float* __restrict__ trans, const int* __restrict__ lens,
                  const float* __restrict__ fbuf, float* __restrict__ wsf) {
  const int w = blockIdx.x;
  const int lane = threadIdx.x;
  const int h = lane >> 5;
  const int c31 = lane & 31;
  const int chain = w * 32 + c31;
  const int len = lens[chain];
  const bool hi = (h == 1);

  // ---- A fragments: A[T][c], A[m][k] = exp(trans[state_in][state_out]) ----
  bh8 afr[2][4];
#pragma unroll
  for (int T = 0; T < 2; ++T)
#pragma unroll
    for (int c = 0; c < 4; ++c) {
      float ev[8];
#pragma unroll
      for (int d = 0; d < 8; ++d) {
        int si = 16 * c + 8 * h + d, so = 32 * T + c31;
        ev[d] = (si < LL && so < LL) ? __expf(trans[si * LL + so]) : 0.f;
      }
      ux4 dw = {cvtpk_bf16(ev[0], ev[1]), cvtpk_bf16(ev[2], ev[3]),
                cvtpk_bf16(ev[4], ev[5]), cvtpk_bf16(ev[6], ev[7])};
      afr[T][c] = __builtin_bit_cast(bh8, dw);
    }

  // ---- exp(trans[s][END]) in D layout ----
  float ee0[16], ee1[16];
#pragma unroll
  for (int r = 0; r < 16; ++r) {
    int sa = (r & 3) + 8 * (r >> 2) + 4 * h;
    ee0[r] = __expf(trans[sa * LL + END_I]);  // sa <= 31 < 50
    int s1 = 32 + sa;
    ee1[r] = (s1 < LL) ? __expf(trans[s1 * LL + END_I]) : 0.f;
  }

  // ---- f prefetch, 4 deep (covers ~HBM latency at ~400cy/step) ----
  const fx4* __restrict__ fp = (const fx4*)fbuf;
  fx4 fqA[8], fqB[8], fqC[8], fqD[8];
  auto LOADF = [&](int t, fx4(&fq)[8]) {
    size_t bqd = ((size_t)t * NW + w) * 512 + lane;
#pragma unroll
    for (int i = 0; i < 8; ++i) fq[i] = fp[bqd + i * 64];
  };
  LOADF(0, fqA);
  LOADF(1, fqB);
  LOADF(2, fqC);
  LOADF(3, fqD);

  int cnt = 0, cc = 0;
  float Zc = 1.0f;
  float sp = 1.0f;    // pending per-chain scale (applied to next step's fq)
  bool pend = false;  // wave-uniform: any chain pending
  bh8 bq[4];
  fx16 z16 = {};

  // ---- step tail: capture -> detect-rescale -> pack+swap -> bq ----
  auto TAIL = [&](int t, float(&d0)[16], float(&d1)[16]) {
    // capture BEFORE detect (d and cnt are a consistent pair here)
    if (__any(len == t + 1)) {
      float z = 0.f;
#pragma unroll
      for (int r = 0; r < 16; ++r) z = fmaf(d0[r], ee0[r], z);
#pragma unroll
      for (int r = 0; r < 16; ++r) z = fmaf(d1[r], ee1[r], z);
      z += xpart(z, hi);
      if (len == t + 1) {
        Zc = z;
        cc = cnt;
      }
    }
    pend = false;
    sp = 1.0f;
    if (t & 1) {  // detect every 2nd step; apply lazily next step
      float mm[8];
#pragma unroll
      for (int r = 0; r < 8; ++r)
        mm[r] = fmaxf(fmaxf(d0[r], d0[r + 8]), fmaxf(d1[r], d1[r + 8]));
      mm[0] = fmaxf(mm[0], mm[4]);
      mm[1] = fmaxf(mm[1], mm[5]);
      mm[2] = fmaxf(mm[2], mm[6]);
      mm[3] = fmaxf(mm[3], mm[7]);
      float m = fmaxf(fmaxf(mm[0], mm[2]), fmaxf(mm[1], mm[3]));
      m = fmaxf(m, xpart(m, hi));  // chain max across lane pair
      bool trig = (m >= 0x1p64f);
      if (__any(trig)) {
        sp = trig ? 0x1p-64f : 1.0f;
        cnt += trig ? 1 : 0;
        pend = true;
      }
    }
    // pack D -> bf16 pair dwords; half-exchange via permlane32_swap:
    // after pls(P[a],P[b]): P[a] = {own lo-pair | partner's P[b]},
    //                       P[b] = {partner's P[a] | own hi-pair}
    unsigned int P0[8], P1[8];
#pragma unroll
    for (int p = 0; p < 8; ++p) {
      P0[p] = cvtpk_bf16(d0[2 * p], d0[2 * p + 1]);
      P1[p] = cvtpk_bf16(d1[2 * p], d1[2 * p + 1]);
    }
    pls(P0[0], P0[2]);
    pls(P0[1], P0[3]);
    pls(P0[4], P0[6]);
    pls(P0[5], P0[7]);
    pls(P1[0], P1[2]);
    pls(P1[1], P1[3]);
    pls(P1[4], P1[6]);
    pls(P1[5], P1[7]);
    ux4 w0 = {P0[0], P0[1], P0[2], P0[3]};
    ux4 w1 = {P0[4], P0[5], P0[6], P0[7]};
    ux4 w2 = {P1[0], P1[1], P1[2], P1[3]};
    ux4 w3 = {P1[4], P1[5], P1[6], P1[7]};
    bq[0] = __builtin_bit_cast(bh8, w0);
    bq[1] = __builtin_bit_cast(bh8, w1);
    bq[2] = __builtin_bit_cast(bh8, w2);
    bq[3] = __builtin_bit_cast(bh8, w3);
  };

  // ---- t = 0: q0 = exp(trans[START][s]) * f0 ----
  {
    float d0[16], d1[16];
#pragma unroll
    for (int r = 0; r < 16; ++r) {
      int sa = (r & 3) + 8 * (r >> 2) + 4 * h;
      float e0 = __expf(trans[START_I * LL + sa]);
      int s1 = 32 + sa;
      float e1 = (s1 < LL) ? __expf(trans[START_I * LL + s1]) : 0.f;
      d0[r] = e0 * fqA[r >> 2][r & 3];
      d1[r] = e1 * fqA[4 + (r >> 2)][r & 3];
    }
    TAIL(0, d0, d1);
    LOADF(4, fqA);
  }

  auto STEP = [&](int t, fx4(&fq)[8]) {
    fx16 ac0, ac1;
    ac0 = __builtin_amdgcn_mfma_f32_32x32x16_bf16(afr[0][0], bq[0], z16, 0, 0, 0);
    ac1 = __builtin_amdgcn_mfma_f32_32x32x16_bf16(afr[1][0], bq[0], z16, 0, 0, 0);
    ac0 = __builtin_amdgcn_mfma_f32_32x32x16_bf16(afr[0][1], bq[1], ac0, 0, 0, 0);
    ac1 = __builtin_amdgcn_mfma_f32_32x32x16_bf16(afr[1][1], bq[1], ac1, 0, 0, 0);
    ac0 = __builtin_amdgcn_mfma_f32_32x32x16_bf16(afr[0][2], bq[2], ac0, 0, 0, 0);
    ac1 = __builtin_amdgcn_mfma_f32_32x32x16_bf16(afr[1][2], bq[2], ac1, 0, 0, 0);
    ac0 = __builtin_amdgcn_mfma_f32_32x32x16_bf16(afr[0][3], bq[3], ac0, 0, 0, 0);
    ac1 = __builtin_amdgcn_mfma_f32_32x32x16_bf16(afr[1][3], bq[3], ac1, 0, 0, 0);
    if (pend) {  // apply pending rescale to fq while MFMAs are in flight
#pragma unroll
      for (int i = 0; i < 8; ++i) {
        fq[i][0] *= sp;
        fq[i][1] *= sp;
        fq[i][2] *= sp;
        fq[i][3] *= sp;
      }
    }
    float d0[16], d1[16];
#pragma unroll
    for (int r = 0; r < 16; ++r) {
      d0[r] = ac0[r] * fq[r >> 2][r & 3];
      d1[r] = ac1[r] * fq[4 + (r >> 2)][r & 3];
    }
    if (t + 4 < TT) LOADF(t + 4, fq);
    TAIL(t, d0, d1);
  };

  // steps 1..1023; rotation B,C,D,A; loop covers 1..1020, tail 1021..1023
  for (int t = 1; t + 3 < TT; t += 4) {
    STEP(t, fqB);
    STEP(t + 1, fqC);
    STEP(t + 2, fqD);
    STEP(t + 3, fqA);
  }
  STEP(TT - 3, fqB);
  STEP(TT - 2, fqC);
  STEP(TT - 1, fqD);

  if (lane < 32)
    wsf[chain] = (float)cc * 44.361419555836498f + __logf(Zc);
}

// ============================================================================
// Legacy fallback (proven round-3 kernel), used when ws_size < 64 MB staging.
// ============================================================================
__global__ __launch_bounds__(64) __attribute__((amdgpu_waves_per_eu(1, 1)))
void crf_fwd_legacy(
    const float* __restrict__ lstm, const float* __restrict__ trans,
    const int* __restrict__ lens, const int* __restrict__ tags,
    float* __restrict__ ws) {
  const int b = blockIdx.x;
  const int lane = threadIdx.x;
  const bool act = lane < LL;
  const int cl = act ? lane : (LL - 1);
  const int len = lens[b];

  float e[LL];
#pragma unroll
  for (int i = 0; i < LL; ++i) {
    float ev = __expf(trans[i * LL + cl]);
    e[i] = act ? ev : 0.0f;
  }
  const float* __restrict__ base = lstm + (size_t)b * TT * LL + cl;
  float q = act ? __expf(trans[START_I * LL + lane] + base[0]) : 0.0f;
  int cnt = 0;
  float s_pend = 1.0f;

  auto STEP = [&](float em) {
    float f = __expf(em) * s_pend;
    float acc0 = 0.f, acc1 = 0.f, acc2 = 0.f, acc3 = 0.f;
#pragma unroll
    for (int i = 0; i < 48; i += 4) {
      acc0 = fmaf(rdlane(q, i + 0), e[i + 0], acc0);
      acc1 = fmaf(rdlane(q, i + 1), e[i + 1], acc1);
      acc2 = fmaf(rdlane(q, i + 2), e[i + 2], acc2);
      acc3 = fmaf(rdlane(q, i + 3), e[i + 3], acc3);
    }
    acc0 = fmaf(rdlane(q, 48), e[48], acc0);
    acc1 = fmaf(rdlane(q, 49), e[49], acc1);
    float qn = ((acc0 + acc1) + (acc2 + acc3)) * f;
    unsigned long long up = __ballot(qn >= 0x1p64f);
    unsigned long long dn = __ballot(qn >= 0x1p-64f);
    s_pend = up ? 0x1p-64f : (dn ? 1.0f : 0x1p64f);
    cnt += up ? 1 : (dn ? 0 : -1);
    q = qn;
  };

  float ebuf[8];
  const float* p = base + LL;
#pragma unroll
  for (int k = 0; k < 8; ++k) ebuf[k] = p[k * LL];
  const int nb = (len - 1) >> 3;
  const int rem = (len - 1) & 7;
  for (int blk = 0; blk < nb; ++blk) {
    const float* pf = p + 8 * LL;
    if (blk < 126) {
#pragma unroll
      for (int u = 0; u < 8; ++u) {
        STEP(ebuf[u]);
        ebuf[u] = pf[u * LL];
      }
    } else {
#pragma unroll
      for (int u = 0; u < 8; ++u) {
        STEP(ebuf[u]);
        int tn = 9 + 8 * blk + u;
        if (tn < TT) ebuf[u] = pf[u * LL];
      }
    }
    p = pf;
  }
  for (int u = 0; u < rem; ++u) STEP(ebuf[u]);
  q *= s_pend;

  float wv = 0.0f;
  if (act) wv = q * __expf(trans[lane * LL + END_I]);
#pragma unroll
  for (int off = 32; off > 0; off >>= 1) wv += __shfl_xor(wv, off, 64);
  float unl = (float)cnt * 44.361419555836498f + __logf(wv);

  const int* tg = tags + (size_t)b * TT;
  float lab = 0.0f;
  for (int t0 = 0; t0 < len; t0 += 64) {
    int t = t0 + lane;
    if (t >= 1 && t < len) {
      int tp = tg[t - 1];
      int tc = tg[t];
      lab += trans[tp * LL + tc] + lstm[((size_t)b * TT + t) * LL + tc];
    }
  }
#pragma unroll
  for (int off = 32; off > 0; off >>= 1) lab += __shfl_xor(lab, off, 64);

  if (lane == 0) {
    int tg0 = tg[0];
    float begin = trans[START_I * LL + tg0] + lstm[(size_t)b * TT * LL + tg0];
    int tgl = tg[len - 1];
    float endv = trans[tgl * LL + END_I];
    ws[b] = unl;
    ws[BB + 4 * b] = lab + begin + endv;
    ws[BB + 4 * b + 1] = 0.f;
    ws[BB + 4 * b + 2] = 0.f;
    ws[BB + 4 * b + 3] = 0.f;
  }
}

// Deterministic final reduce: base[0..255] -> out[0]; base[256..1279] -> out[1]
__global__ __launch_bounds__(256) void crf_reduce(const float* __restrict__ base,
                                                  float* __restrict__ out) {
  __shared__ float sm[8];
  int tid = threadIdx.x;
  float u = base[tid];
  fx4 lv = ((const fx4*)(base + BB))[tid];
  float l = (lv[0] + lv[1]) + (lv[2] + lv[3]);
#pragma unroll
  for (int off = 32; off > 0; off >>= 1) {
    u += __shfl_xor(u, off, 64);
    l += __shfl_xor(l, off, 64);
  }
  int wid = tid >> 6;
  if ((tid & 63) == 0) {
    sm[wid] = u;
    sm[4 + wid] = l;
  }
  __syncthreads();
  if (tid == 0) {
    out[0] = (sm[0] + sm[1]) + (sm[2] + sm[3]);
    out[1] = (sm[4] + sm[5]) + (sm[6] + sm[7]);
  }
}

extern "C" void kernel_launch(void* const* d_in, const int* in_sizes, int n_in,
                              void* d_out, int out_size, void* d_ws, size_t ws_size,
                              hipStream_t stream) {
  const float* lstm = (const float*)d_in[0];
  const float* trans = (const float*)d_in[1];
  const int* lens = (const int*)d_in[2];
  const int* tags = (const int*)d_in[3];
  float* out = (float*)d_out;

  size_t need = (size_t)FOFF * 4 + (size_t)(BB * 5) * 4;
  if (ws_size >= need) {
    float* fbuf = (float*)d_ws;
    float* wsf = fbuf + FOFF;
    crf_prep<<<dim3(NPREB + BB), dim3(256), 0, stream>>>(lstm, trans, lens, tags,
                                                         fbuf, wsf);
    crf_fwd_mfma<<<dim3(NW), dim3(64), 0, stream>>>(trans, lens, fbuf, wsf);
    crf_reduce<<<dim3(1), dim3(256), 0, stream>>>(wsf, out);
  } else {
    float* wsf = (float*)d_ws;
    crf_fwd_legacy<<<dim3(BB), dim3(64), 0, stream>>>(lstm, trans, lens, tags, wsf);
    crf_reduce<<<dim3(1), dim3(256), 0, stream>>>(wsf, out);
  }
}